// Round 10
// baseline (344.929 us; speedup 1.0000x reference)
//
#include <hip/hip_runtime.h>
#include <hip/hip_bf16.h>

// Problem constants
#define Bn 4
#define Tn 2048
#define Cn 1024
#define Hn 16
#define Dn 64
#define Kdim 1024

typedef __bf16 bf16x8 __attribute__((ext_vector_type(8)));
typedef float f32x4 __attribute__((ext_vector_type(4)));
union B8 { uint4 u; bf16x8 f; ushort s[8]; };

static __device__ __forceinline__ ushort f2bf(float x) {
    __hip_bfloat16 h = __float2bfloat16(x);
    return *(ushort*)&h;
}

#define AS1 __attribute__((address_space(1)))
#define AS3 __attribute__((address_space(3)))

static __device__ __forceinline__ void gload_lds16(const ushort* g, ushort* l) {
    __builtin_amdgcn_global_load_lds((AS1 const uint4*)(const void*)g,
                                     (AS3 uint4*)(void*)l, 16, 0, 0);
}

// ---------------------------------------------------------------------------
// fp32 -> bf16 cast (layout preserved). n multiple of 8.
// ---------------------------------------------------------------------------
__global__ __launch_bounds__(256) void cvt_bf16(
    const float* __restrict__ src, ushort* __restrict__ dst, int n)
{
    int i = (blockIdx.x * 256 + threadIdx.x) * 8;
    if (i >= n) return;
    float4 a = *(const float4*)&src[i];
    float4 b = *(const float4*)&src[i + 4];
    ushort4 o0, o1;
    o0.x = f2bf(a.x); o0.y = f2bf(a.y); o0.z = f2bf(a.z); o0.w = f2bf(a.w);
    o1.x = f2bf(b.x); o1.y = f2bf(b.y); o1.z = f2bf(b.z); o1.w = f2bf(b.w);
    *(ushort4*)&dst[i] = o0;
    *(ushort4*)&dst[i + 4] = o1;
}

// ---------------------------------------------------------------------------
// W[K,N] fp32 -> Wt[N,K] bf16 (32x32 LDS tile transpose)
// ---------------------------------------------------------------------------
__global__ __launch_bounds__(256) void transpose_bf16(
    const float* __restrict__ W, ushort* __restrict__ Wt, int N)
{
    __shared__ float Ls[32][33];
    const int k0 = blockIdx.y * 32, n0 = blockIdx.x * 32;
    const int tx = threadIdx.x & 31, ty = threadIdx.x >> 5;
    #pragma unroll
    for (int i = 0; i < 4; i++) {
        int r = ty + i * 8;
        Ls[r][tx] = W[(size_t)(k0 + r) * N + n0 + tx];
    }
    __syncthreads();
    #pragma unroll
    for (int i = 0; i < 4; i++) {
        int r = ty + i * 8;
        Wt[(size_t)(n0 + r) * Kdim + k0 + tx] = f2bf(Ls[tx][r]);
    }
}

// ---------------------------------------------------------------------------
// bf16 MFMA GEMM (m97 structure): C[M,N] = A[M,K] @ Bt[N,K]^T (+bias).
// EPI 0: fp32 out + bias.
// EPI 1: bf16 Q[B,H,T,D] (pre-scaled by D^-0.5*log2(e)), K[B,H,T,D],
//        V^T[B,H,D,T]. Epilogue round-trips each wave's 64x64 tile through
//        LDS (XOR bank swizzle) -> fully coalesced uint4 global stores.
// ---------------------------------------------------------------------------
template <int EPI>
__global__ __launch_bounds__(256) void gemm_bt(
    const ushort* __restrict__ A, const ushort* __restrict__ Bt,
    const float* __restrict__ bias,
    float* __restrict__ Out, ushort* __restrict__ Qb,
    ushort* __restrict__ Kb, ushort* __restrict__ Vtb)
{
    const int m0 = blockIdx.y * 128;
    const int n0 = blockIdx.x * 128;
    const int t  = threadIdx.x;
    const int wave = t >> 6, lane = t & 63;
    const int ln = lane & 15, quad = lane >> 4;
    const int wm = wave >> 1, wn = wave & 1;

    __shared__ ushort As[128 * 64];
    __shared__ ushort Bs[128 * 64];

    f32x4 acc[4][4] = {};

    for (int k0 = 0; k0 < Kdim; k0 += 64) {
        __syncthreads();
        #pragma unroll
        for (int it = 0; it < 4; it++) {
            int c = it * 256 + wave * 64 + lane;
            int row = c >> 3, seg = c & 7;
            int gseg = seg ^ (row & 7);
            gload_lds16(&A [(size_t)(m0 + row) * Kdim + k0 + gseg * 8], &As[c * 8]);
            gload_lds16(&Bt[(size_t)(n0 + row) * Kdim + k0 + gseg * 8], &Bs[c * 8]);
        }
        __syncthreads();

        #pragma unroll
        for (int ks = 0; ks < 2; ks++) {
            bf16x8 af[4], bf[4];
            #pragma unroll
            for (int mm = 0; mm < 4; mm++) {
                int row = wm * 64 + mm * 16 + ln;
                int seg = (ks * 4 + quad) ^ (ln & 7);
                B8 tmp; tmp.u = *(const uint4*)&As[row * 64 + seg * 8];
                af[mm] = tmp.f;
            }
            #pragma unroll
            for (int nn = 0; nn < 4; nn++) {
                int row = wn * 64 + nn * 16 + ln;
                int seg = (ks * 4 + quad) ^ (ln & 7);
                B8 tmp; tmp.u = *(const uint4*)&Bs[row * 64 + seg * 8];
                bf[nn] = tmp.f;
            }
            #pragma unroll
            for (int mm = 0; mm < 4; mm++)
                #pragma unroll
                for (int nn = 0; nn < 4; nn++)
                    acc[mm][nn] = __builtin_amdgcn_mfma_f32_16x16x32_bf16(
                        af[mm], bf[nn], acc[mm][nn], 0, 0, 0);
        }
    }

    if (EPI == 0) {
        #pragma unroll
        for (int nn = 0; nn < 4; nn++) {
            int n = n0 + wn * 64 + nn * 16 + ln;
            float bv = bias[n];
            #pragma unroll
            for (int mm = 0; mm < 4; mm++) {
                int mbase = m0 + wm * 64 + mm * 16 + quad * 4;
                #pragma unroll
                for (int reg = 0; reg < 4; reg++)
                    Out[(size_t)(mbase + reg) * 1024 + n] = acc[mm][nn][reg] + bv;
            }
        }
    } else {
        const int nb = n0 + wn * 64;
        const int which = nb >> 10;            // 0=Q 1=K 2=V
        const int h = (nb & 1023) >> 6;
        const float scale = (which == 0) ? 0.125f * 1.44269504088896f : 1.0f;
        const int b_ = m0 >> 11;               // 128-row tile within one batch
        const int t0 = (m0 & 2047) + wm * 64;

        __syncthreads();   // fragments consumed; reuse As/Bs as transpose pads
        ushort* tile = ((wave & 2) ? Bs : As) + (wave & 1) * 4096;  // 64x64/wave

        if (which == 2) {
            // LDS tile [n=d][m=token] (XOR-swizzled), rows -> [B,H,D,T]
            #pragma unroll
            for (int nn = 0; nn < 4; nn++) {
                float bv = bias[nb + nn * 16 + ln];
                #pragma unroll
                for (int mm = 0; mm < 4; mm++)
                    #pragma unroll
                    for (int reg = 0; reg < 4; reg++) {
                        int m = mm * 16 + quad * 4 + reg;
                        int n = nn * 16 + ln;
                        tile[n * 64 + (m ^ (((n >> 1) & 7) * 8))] =
                            f2bf(acc[mm][nn][reg] + bv);
                    }
            }
            #pragma unroll
            for (int it = 0; it < 8; it++) {
                int idx = it * 64 + lane;
                int row = idx >> 3, seg = idx & 7;   // row = d, seg = token/8
                uint4 v = *(const uint4*)&tile[row * 64 +
                              ((seg * 8) ^ (((row >> 1) & 7) * 8))];
                *(uint4*)&Vtb[((size_t)((b_ * Hn + h) * Dn) + row) * Tn + t0 + seg * 8] = v;
            }
        } else {
            // LDS tile [m=token][n=d] (XOR-swizzled), rows -> [B,H,T,D]
            ushort* dst = (which == 0) ? Qb : Kb;
            #pragma unroll
            for (int nn = 0; nn < 4; nn++) {
                float bv = bias[nb + nn * 16 + ln];
                #pragma unroll
                for (int mm = 0; mm < 4; mm++)
                    #pragma unroll
                    for (int reg = 0; reg < 4; reg++) {
                        int m = mm * 16 + quad * 4 + reg;
                        int n = nn * 16 + ln;
                        tile[m * 64 + (n ^ (((m >> 1) & 7) * 8))] =
                            f2bf((acc[mm][nn][reg] + bv) * scale);
                    }
            }
            #pragma unroll
            for (int it = 0; it < 8; it++) {
                int idx = it * 64 + lane;
                int row = idx >> 3, seg = idx & 7;   // row = token, seg = d/8
                uint4 v = *(const uint4*)&tile[row * 64 +
                              ((seg * 8) ^ (((row >> 1) & 7) * 8))];
                *(uint4*)&dst[((size_t)((b_ * Hn + h) * Tn) + t0 + row) * Dn + seg * 8] = v;
            }
        }
    }
}

// ---------------------------------------------------------------------------
// Flash attention v7: v6 + VGPR diet for 3 blocks/CU residency.
// __launch_bounds__(256,3) caps unified VGPRs at ~170; V fragments use a
// 2-deep rolling buffer (32 regs, was 64): slots for PV passes 0/1 issue
// right after the barrier (hidden under QK), pass p prefetches pass p+2.
// ---------------------------------------------------------------------------
__global__ __launch_bounds__(256, 3) void attn_mfma(
    const ushort* __restrict__ Qb, const ushort* __restrict__ Kb,
    const ushort* __restrict__ Vtb, ushort* __restrict__ Ob)
{
    const int bh   = blockIdx.x;       // 0..63 (fastest-varying)
    const int qt   = 15 - blockIdx.y;  // heavy tiles first in block-ID order
    const int t    = threadIdx.x;
    const int wave = t >> 6, lane = t & 63;
    const int ln   = lane & 15, quad = lane >> 4;

    __shared__ ushort Ks[2][128 * 64];  // [key][d], xor-swizzled segs, 2x16KB
    __shared__ ushort Ps[4][32 * 34];   // per-wave P slice [q][key(32)+pad]

    const ushort* KgB = Kb  + (size_t)bh * Tn * Dn;
    const ushort* VgB = Vtb + (size_t)bh * Dn * Tn;
    const int b_ = bh >> 4, h = bh & 15;

    #define STAGE_K(kc, buf)                                                   \
        do {                                                                   \
            _Pragma("unroll")                                                  \
            for (int it = 0; it < 4; it++) {                                   \
                int c = it * 256 + wave * 64 + lane;                           \
                int row = c >> 3, seg = c & 7;                                 \
                int gs = seg ^ (row & 7);                                      \
                gload_lds16(&KgB[(size_t)((kc) * 128 + row) * Dn + gs * 8],    \
                            &Ks[buf][c * 8]);                                  \
            }                                                                  \
        } while (0)

    int cur = 0;
    STAGE_K(0, 0);

    const int q0 = qt * 128;

    const ushort* Qg = Qb + ((size_t)bh * Tn + q0 + wave * 32) * Dn;
    bf16x8 qf[2][2];
    #pragma unroll
    for (int ns = 0; ns < 2; ns++)
        #pragma unroll
        for (int ks = 0; ks < 2; ks++) {
            B8 tmp; tmp.u = *(const uint4*)&Qg[(ns * 16 + ln) * 64 + ks * 32 + quad * 8];
            qf[ns][ks] = tmp.f;
        }

    f32x4 Oacc[4][2] = {};   // O^T [d-subtile][ns], lane ln = q
    float m_r[2] = {-1e30f, -1e30f}, l_r[2] = {0.f, 0.f};

    for (int kc = 0; kc <= qt; kc++) {
        __syncthreads();   // publishes K(kc); drains prefetch issued last iter

        // V^T rolling buffer: slots for PV passes 0/1, hidden under QK
        B8 vfr[2][4];      // [slot][d-subtile]
        #pragma unroll
        for (int sl = 0; sl < 2; sl++)
            #pragma unroll
            for (int ctd = 0; ctd < 4; ctd++)
                vfr[sl][ctd].u = *(const uint4*)&VgB[
                    (size_t)(ctd * 16 + ln) * Tn + kc * 128 + sl * 32 + quad * 8];

        if (kc < qt) STAGE_K(kc + 1, cur ^ 1);   // prefetch next chunk

        // S^T = K Q^T
        const ushort* Kc = Ks[cur];
        f32x4 S[8][2] = {};
        #pragma unroll
        for (int ks = 0; ks < 2; ks++)
            #pragma unroll
            for (int ct = 0; ct < 8; ct++) {
                B8 a; a.u = *(const uint4*)&Kc[(ct * 16 + ln) * 64 +
                                               (((ks * 4 + quad) ^ (ln & 7)) * 8)];
                #pragma unroll
                for (int ns = 0; ns < 2; ns++)
                    S[ct][ns] = __builtin_amdgcn_mfma_f32_16x16x32_bf16(
                        a.f, qf[ns][ks], S[ct][ns], 0, 0, 0);
            }

        if (kc == qt) {   // causal mask on diagonal chunk
            #pragma unroll
            for (int ct = 0; ct < 8; ct++) {
                int keyl = ct * 16 + quad * 4;
                #pragma unroll
                for (int ns = 0; ns < 2; ns++) {
                    int ql = wave * 32 + ns * 16 + ln;
                    #pragma unroll
                    for (int reg = 0; reg < 4; reg++)
                        if (keyl + reg > ql) S[ct][ns][reg] = -1e30f;
                }
            }
        }

        // per-lane online softmax stats (q = ln; reduce over quads)
        float alpha[2], ssum[2] = {0.f, 0.f};
        #pragma unroll
        for (int ns = 0; ns < 2; ns++) {
            float pm = -1e30f;
            #pragma unroll
            for (int ct = 0; ct < 8; ct++)
                #pragma unroll
                for (int reg = 0; reg < 4; reg++)
                    pm = fmaxf(pm, S[ct][ns][reg]);
            pm = fmaxf(pm, __shfl_xor(pm, 16));
            pm = fmaxf(pm, __shfl_xor(pm, 32));
            float mn = fmaxf(m_r[ns], pm);
            alpha[ns] = exp2f(m_r[ns] - mn);
            m_r[ns] = mn;
            #pragma unroll
            for (int ctd = 0; ctd < 4; ctd++)
                Oacc[ctd][ns] *= alpha[ns];
        }

        // 4 passes: write 32-key P slice, consume with PV, prefetch V p+2
        ushort* Pw = Ps[wave];
        #pragma unroll
        for (int p = 0; p < 4; p++) {
            #pragma unroll
            for (int ct_h = 0; ct_h < 2; ct_h++) {
                int ct = p * 2 + ct_h;
                #pragma unroll
                for (int ns = 0; ns < 2; ns++) {
                    ushort4 o;
                    #pragma unroll
                    for (int reg = 0; reg < 4; reg++) {
                        float pv = exp2f(S[ct][ns][reg] - m_r[ns]);
                        ssum[ns] += pv;
                        ((ushort*)&o)[reg] = f2bf(pv);
                    }
                    *(ushort4*)&Pw[(ns * 16 + ln) * 34 + ct_h * 16 + quad * 4] = o;
                }
            }
            #pragma unroll
            for (int ns = 0; ns < 2; ns++) {
                B8 pfr; pfr.u = *(const uint4*)&Pw[(ns * 16 + ln) * 34 + quad * 8];
                #pragma unroll
                for (int ctd = 0; ctd < 4; ctd++)
                    Oacc[ctd][ns] = __builtin_amdgcn_mfma_f32_16x16x32_bf16(
                        vfr[p & 1][ctd].f, pfr.f, Oacc[ctd][ns], 0, 0, 0);
            }
            if (p < 2) {   // refill just-freed slot with pass p+2's V
                #pragma unroll
                for (int ctd = 0; ctd < 4; ctd++)
                    vfr[p & 1][ctd].u = *(const uint4*)&VgB[
                        (size_t)(ctd * 16 + ln) * Tn + kc * 128 + (p + 2) * 32 + quad * 8];
            }
        }
        #pragma unroll
        for (int ns = 0; ns < 2; ns++) {
            float s = ssum[ns];
            s += __shfl_xor(s, 16);
            s += __shfl_xor(s, 32);
            l_r[ns] = l_r[ns] * alpha[ns] + s;
        }
        cur ^= 1;
    }

    // epilogue: bf16 attn_out [B*T][C]; lane ln = token, regs = d
    #pragma unroll
    for (int ns = 0; ns < 2; ns++) {
        float inv = 1.0f / l_r[ns];
        int token = q0 + wave * 32 + ns * 16 + ln;
        ushort* dst = Ob + ((size_t)(b_ * Tn + token)) * Cn + h * 64;
        #pragma unroll
        for (int ctd = 0; ctd < 4; ctd++) {
            ushort4 o;
            #pragma unroll
            for (int reg = 0; reg < 4; reg++)
                ((ushort*)&o)[reg] = f2bf(Oacc[ctd][ns][reg] * inv);
            *(ushort4*)&dst[ctd * 16 + quad * 4] = o;
        }
    }
    #undef STAGE_K
}

// ---------------------------------------------------------------------------
extern "C" void kernel_launch(void* const* d_in, const int* in_sizes, int n_in,
                              void* d_out, int out_size, void* d_ws, size_t ws_size,
                              hipStream_t stream) {
    const float* X     = (const float*)d_in[0];
    const float* qkv_w = (const float*)d_in[1];
    const float* qkv_b = (const float*)d_in[2];
    const float* o_w   = (const float*)d_in[3];
    const float* o_b   = (const float*)d_in[4];
    float* out = (float*)d_out;

    const size_t BTC = (size_t)Bn * Tn * Cn;     // 8388608
    ushort* Xb  = (ushort*)d_ws;                 // bf16 [8192,1024]
    ushort* Wqt = Xb  + BTC;                     // bf16 [3072,1024]
    ushort* Wot = Wqt + 3 * Cn * Cn;             // bf16 [1024,1024]
    ushort* Qb  = Wot + Cn * Cn;                 // bf16 [B,H,T,D]
    ushort* Kb  = Qb  + BTC;
    ushort* Vtb = Kb  + BTC;                     // bf16 [B,H,D,T]
    ushort* Ao  = Vtb + BTC;                     // bf16 [B*T,C]

    cvt_bf16<<<dim3((int)(BTC / 8 / 256)), 256, 0, stream>>>(X, Xb, (int)BTC);
    transpose_bf16<<<dim3(3 * Cn / 32, Kdim / 32), 256, 0, stream>>>(qkv_w, Wqt, 3 * Cn);
    transpose_bf16<<<dim3(Cn / 32, Kdim / 32), 256, 0, stream>>>(o_w, Wot, Cn);

    gemm_bt<1><<<dim3(3 * Cn / 128, 8192 / 128), 256, 0, stream>>>(
        Xb, Wqt, qkv_b, nullptr, Qb, Kb, Vtb);
    attn_mfma<<<dim3(Bn * Hn, 16), 256, 0, stream>>>(Qb, Kb, Vtb, Ao);
    gemm_bt<0><<<dim3(Cn / 128, 8192 / 128), 256, 0, stream>>>(
        Ao, Wot, o_b, out, nullptr, nullptr, nullptr);
}

// Round 11
// 341.962 us; speedup vs baseline: 1.0087x; 1.0087x over previous
//
#include <hip/hip_runtime.h>
#include <hip/hip_bf16.h>

// Problem constants
#define Bn 4
#define Tn 2048
#define Cn 1024
#define Hn 16
#define Dn 64
#define Kdim 1024

typedef __bf16 bf16x8 __attribute__((ext_vector_type(8)));
typedef __bf16 bf16x4 __attribute__((ext_vector_type(4)));
typedef short s16x4 __attribute__((ext_vector_type(4)));
typedef float f32x4 __attribute__((ext_vector_type(4)));
union B8 { uint4 u; bf16x8 f; ushort s[8]; };
union B4 { uint2 u; s16x4 s; bf16x4 f; ushort h[4]; };

static __device__ __forceinline__ ushort f2bf(float x) {
    __hip_bfloat16 h = __float2bfloat16(x);
    return *(ushort*)&h;
}
static __device__ __forceinline__ uint pk2bf(float lo, float hi) {
    return (uint)f2bf(lo) | ((uint)f2bf(hi) << 16);
}

// PV matmul: 16x16x16 bf16 MFMA (B-operand layout k=quad*4+j matches the
// C-layout of S, so P feeds straight from registers — no LDS round-trip).
static __device__ __forceinline__ f32x4 pv_mfma(B4 a, B4 b, f32x4 c) {
#if __has_builtin(__builtin_amdgcn_mfma_f32_16x16x16bf16_1k)
    return __builtin_amdgcn_mfma_f32_16x16x16bf16_1k(a.s, b.s, c, 0, 0, 0);
#elif __has_builtin(__builtin_amdgcn_mfma_f32_16x16x16_bf16)
    return __builtin_amdgcn_mfma_f32_16x16x16_bf16(a.f, b.f, c, 0, 0, 0);
#else
    asm("v_mfma_f32_16x16x16_bf16 %0, %1, %2, %0" : "+v"(c) : "v"(a.u), "v"(b.u));
    return c;
#endif
}

#define AS1 __attribute__((address_space(1)))
#define AS3 __attribute__((address_space(3)))

static __device__ __forceinline__ void gload_lds16(const ushort* g, ushort* l) {
    __builtin_amdgcn_global_load_lds((AS1 const uint4*)(const void*)g,
                                     (AS3 uint4*)(void*)l, 16, 0, 0);
}

// ---------------------------------------------------------------------------
// fp32 -> bf16 cast (layout preserved). n multiple of 8.
// ---------------------------------------------------------------------------
__global__ __launch_bounds__(256) void cvt_bf16(
    const float* __restrict__ src, ushort* __restrict__ dst, int n)
{
    int i = (blockIdx.x * 256 + threadIdx.x) * 8;
    if (i >= n) return;
    float4 a = *(const float4*)&src[i];
    float4 b = *(const float4*)&src[i + 4];
    ushort4 o0, o1;
    o0.x = f2bf(a.x); o0.y = f2bf(a.y); o0.z = f2bf(a.z); o0.w = f2bf(a.w);
    o1.x = f2bf(b.x); o1.y = f2bf(b.y); o1.z = f2bf(b.z); o1.w = f2bf(b.w);
    *(ushort4*)&dst[i] = o0;
    *(ushort4*)&dst[i + 4] = o1;
}

// ---------------------------------------------------------------------------
// W[K,N] fp32 -> Wt[N,K] bf16 (32x32 LDS tile transpose)
// ---------------------------------------------------------------------------
__global__ __launch_bounds__(256) void transpose_bf16(
    const float* __restrict__ W, ushort* __restrict__ Wt, int N)
{
    __shared__ float Ls[32][33];
    const int k0 = blockIdx.y * 32, n0 = blockIdx.x * 32;
    const int tx = threadIdx.x & 31, ty = threadIdx.x >> 5;
    #pragma unroll
    for (int i = 0; i < 4; i++) {
        int r = ty + i * 8;
        Ls[r][tx] = W[(size_t)(k0 + r) * N + n0 + tx];
    }
    __syncthreads();
    #pragma unroll
    for (int i = 0; i < 4; i++) {
        int r = ty + i * 8;
        Wt[(size_t)(n0 + r) * Kdim + k0 + tx] = f2bf(Ls[tx][r]);
    }
}

// ---------------------------------------------------------------------------
// bf16 MFMA GEMM (m97 structure): C[M,N] = A[M,K] @ Bt[N,K]^T (+bias).
// EPI 0: fp32 out + bias.
// EPI 1: bf16 Q[B,H,T,D] (pre-scaled by D^-0.5*log2(e)), K[B,H,T,D],
//        V^T[B,H,D,T]. Epilogue round-trips each wave's 64x64 tile through
//        LDS (XOR bank swizzle) -> fully coalesced uint4 global stores.
// ---------------------------------------------------------------------------
template <int EPI>
__global__ __launch_bounds__(256) void gemm_bt(
    const ushort* __restrict__ A, const ushort* __restrict__ Bt,
    const float* __restrict__ bias,
    float* __restrict__ Out, ushort* __restrict__ Qb,
    ushort* __restrict__ Kb, ushort* __restrict__ Vtb)
{
    const int m0 = blockIdx.y * 128;
    const int n0 = blockIdx.x * 128;
    const int t  = threadIdx.x;
    const int wave = t >> 6, lane = t & 63;
    const int ln = lane & 15, quad = lane >> 4;
    const int wm = wave >> 1, wn = wave & 1;

    __shared__ ushort As[128 * 64];
    __shared__ ushort Bs[128 * 64];

    f32x4 acc[4][4] = {};

    for (int k0 = 0; k0 < Kdim; k0 += 64) {
        __syncthreads();
        #pragma unroll
        for (int it = 0; it < 4; it++) {
            int c = it * 256 + wave * 64 + lane;
            int row = c >> 3, seg = c & 7;
            int gseg = seg ^ (row & 7);
            gload_lds16(&A [(size_t)(m0 + row) * Kdim + k0 + gseg * 8], &As[c * 8]);
            gload_lds16(&Bt[(size_t)(n0 + row) * Kdim + k0 + gseg * 8], &Bs[c * 8]);
        }
        __syncthreads();

        #pragma unroll
        for (int ks = 0; ks < 2; ks++) {
            bf16x8 af[4], bf[4];
            #pragma unroll
            for (int mm = 0; mm < 4; mm++) {
                int row = wm * 64 + mm * 16 + ln;
                int seg = (ks * 4 + quad) ^ (ln & 7);
                B8 tmp; tmp.u = *(const uint4*)&As[row * 64 + seg * 8];
                af[mm] = tmp.f;
            }
            #pragma unroll
            for (int nn = 0; nn < 4; nn++) {
                int row = wn * 64 + nn * 16 + ln;
                int seg = (ks * 4 + quad) ^ (ln & 7);
                B8 tmp; tmp.u = *(const uint4*)&Bs[row * 64 + seg * 8];
                bf[nn] = tmp.f;
            }
            #pragma unroll
            for (int mm = 0; mm < 4; mm++)
                #pragma unroll
                for (int nn = 0; nn < 4; nn++)
                    acc[mm][nn] = __builtin_amdgcn_mfma_f32_16x16x32_bf16(
                        af[mm], bf[nn], acc[mm][nn], 0, 0, 0);
        }
    }

    if (EPI == 0) {
        #pragma unroll
        for (int nn = 0; nn < 4; nn++) {
            int n = n0 + wn * 64 + nn * 16 + ln;
            float bv = bias[n];
            #pragma unroll
            for (int mm = 0; mm < 4; mm++) {
                int mbase = m0 + wm * 64 + mm * 16 + quad * 4;
                #pragma unroll
                for (int reg = 0; reg < 4; reg++)
                    Out[(size_t)(mbase + reg) * 1024 + n] = acc[mm][nn][reg] + bv;
            }
        }
    } else {
        const int nb = n0 + wn * 64;
        const int which = nb >> 10;            // 0=Q 1=K 2=V
        const int h = (nb & 1023) >> 6;
        const float scale = (which == 0) ? 0.125f * 1.44269504088896f : 1.0f;
        const int b_ = m0 >> 11;               // 128-row tile within one batch
        const int t0 = (m0 & 2047) + wm * 64;

        __syncthreads();   // fragments consumed; reuse As/Bs as transpose pads
        ushort* tile = ((wave & 2) ? Bs : As) + (wave & 1) * 4096;  // 64x64/wave

        if (which == 2) {
            // LDS tile [n=d][m=token] (XOR-swizzled), rows -> [B,H,D,T]
            #pragma unroll
            for (int nn = 0; nn < 4; nn++) {
                float bv = bias[nb + nn * 16 + ln];
                #pragma unroll
                for (int mm = 0; mm < 4; mm++)
                    #pragma unroll
                    for (int reg = 0; reg < 4; reg++) {
                        int m = mm * 16 + quad * 4 + reg;
                        int n = nn * 16 + ln;
                        tile[n * 64 + (m ^ (((n >> 1) & 7) * 8))] =
                            f2bf(acc[mm][nn][reg] + bv);
                    }
            }
            #pragma unroll
            for (int it = 0; it < 8; it++) {
                int idx = it * 64 + lane;
                int row = idx >> 3, seg = idx & 7;   // row = d, seg = token/8
                uint4 v = *(const uint4*)&tile[row * 64 +
                              ((seg * 8) ^ (((row >> 1) & 7) * 8))];
                *(uint4*)&Vtb[((size_t)((b_ * Hn + h) * Dn) + row) * Tn + t0 + seg * 8] = v;
            }
        } else {
            // LDS tile [m=token][n=d] (XOR-swizzled), rows -> [B,H,T,D]
            ushort* dst = (which == 0) ? Qb : Kb;
            #pragma unroll
            for (int nn = 0; nn < 4; nn++) {
                float bv = bias[nb + nn * 16 + ln];
                #pragma unroll
                for (int mm = 0; mm < 4; mm++)
                    #pragma unroll
                    for (int reg = 0; reg < 4; reg++) {
                        int m = mm * 16 + quad * 4 + reg;
                        int n = nn * 16 + ln;
                        tile[m * 64 + (n ^ (((m >> 1) & 7) * 8))] =
                            f2bf((acc[mm][nn][reg] + bv) * scale);
                    }
            }
            #pragma unroll
            for (int it = 0; it < 8; it++) {
                int idx = it * 64 + lane;
                int row = idx >> 3, seg = idx & 7;   // row = token, seg = d/8
                uint4 v = *(const uint4*)&tile[row * 64 +
                              ((seg * 8) ^ (((row >> 1) & 7) * 8))];
                *(uint4*)&dst[((size_t)((b_ * Hn + h) * Tn) + t0 + row) * Dn + seg * 8] = v;
            }
        }
    }
}

// ---------------------------------------------------------------------------
// Flash attention v8: r9 residency config (256,2 — no spills) + PV consumes
// P DIRECTLY FROM REGISTERS via 16x16x16 MFMA (B layout k=quad*4+j == S's
// C-layout rows), eliminating the P LDS round-trip and the Ps buffer.
// V^T fragments: 8B global loads in 16x16x16 A-layout (keys quad*4..+3),
// issued post-barrier, hidden under QK. K double-buffered via
// global_load_lds; grid (64,16) heavy-first; exp2 softmax.
// ---------------------------------------------------------------------------
__global__ __launch_bounds__(256, 2) void attn_mfma(
    const ushort* __restrict__ Qb, const ushort* __restrict__ Kb,
    const ushort* __restrict__ Vtb, ushort* __restrict__ Ob)
{
    const int bh   = blockIdx.x;       // 0..63 (fastest-varying)
    const int qt   = 15 - blockIdx.y;  // heavy tiles first in block-ID order
    const int t    = threadIdx.x;
    const int wave = t >> 6, lane = t & 63;
    const int ln   = lane & 15, quad = lane >> 4;

    __shared__ ushort Ks[2][128 * 64];  // [key][d], xor-swizzled segs, 2x16KB

    const ushort* KgB = Kb  + (size_t)bh * Tn * Dn;
    const ushort* VgB = Vtb + (size_t)bh * Dn * Tn;
    const int b_ = bh >> 4, h = bh & 15;

    #define STAGE_K(kc, buf)                                                   \
        do {                                                                   \
            _Pragma("unroll")                                                  \
            for (int it = 0; it < 4; it++) {                                   \
                int c = it * 256 + wave * 64 + lane;                           \
                int row = c >> 3, seg = c & 7;                                 \
                int gs = seg ^ (row & 7);                                      \
                gload_lds16(&KgB[(size_t)((kc) * 128 + row) * Dn + gs * 8],    \
                            &Ks[buf][c * 8]);                                  \
            }                                                                  \
        } while (0)

    int cur = 0;
    STAGE_K(0, 0);

    const int q0 = qt * 128;

    // Q B-fragments for QK (x32): lane ln = q, d = ks*32 + quad*8 + j
    const ushort* Qg = Qb + ((size_t)bh * Tn + q0 + wave * 32) * Dn;
    bf16x8 qf[2][2];
    #pragma unroll
    for (int ns = 0; ns < 2; ns++)
        #pragma unroll
        for (int ks = 0; ks < 2; ks++) {
            B8 tmp; tmp.u = *(const uint4*)&Qg[(ns * 16 + ln) * 64 + ks * 32 + quad * 8];
            qf[ns][ks] = tmp.f;
        }

    f32x4 Oacc[4][2] = {};   // O^T [d-subtile][ns], lane ln = q
    float m_r[2] = {-1e30f, -1e30f}, l_r[2] = {0.f, 0.f};

    for (int kc = 0; kc <= qt; kc++) {
        __syncthreads();   // publishes K(kc); drains prefetch issued last iter

        // V^T fragments in 16x16x16 A-layout: lane (ln, quad) of (ctd, ct)
        // holds V^T[d = ctd*16+ln][keys ct*16 + quad*4 .. +3] — 8B loads.
        B4 vfr[8][4];      // [ct][d-subtile]
        #pragma unroll
        for (int ct = 0; ct < 8; ct++)
            #pragma unroll
            for (int ctd = 0; ctd < 4; ctd++)
                vfr[ct][ctd].u = *(const uint2*)&VgB[
                    (size_t)(ctd * 16 + ln) * Tn + kc * 128 + ct * 16 + quad * 4];

        if (kc < qt) STAGE_K(kc + 1, cur ^ 1);   // prefetch next chunk

        // S^T = K Q^T (x32): rows = keys (8 ct), cols = q (2 ns)
        const ushort* Kc = Ks[cur];
        f32x4 S[8][2] = {};
        #pragma unroll
        for (int ks = 0; ks < 2; ks++)
            #pragma unroll
            for (int ct = 0; ct < 8; ct++) {
                B8 a; a.u = *(const uint4*)&Kc[(ct * 16 + ln) * 64 +
                                               (((ks * 4 + quad) ^ (ln & 7)) * 8)];
                #pragma unroll
                for (int ns = 0; ns < 2; ns++)
                    S[ct][ns] = __builtin_amdgcn_mfma_f32_16x16x32_bf16(
                        a.f, qf[ns][ks], S[ct][ns], 0, 0, 0);
            }

        if (kc == qt) {   // causal mask on diagonal chunk
            #pragma unroll
            for (int ct = 0; ct < 8; ct++) {
                int keyl = ct * 16 + quad * 4;
                #pragma unroll
                for (int ns = 0; ns < 2; ns++) {
                    int ql = wave * 32 + ns * 16 + ln;
                    #pragma unroll
                    for (int reg = 0; reg < 4; reg++)
                        if (keyl + reg > ql) S[ct][ns][reg] = -1e30f;
                }
            }
        }

        // per-lane online softmax stats (q = ln; reduce over quads)
        float alpha[2], ssum[2] = {0.f, 0.f};
        #pragma unroll
        for (int ns = 0; ns < 2; ns++) {
            float pm = -1e30f;
            #pragma unroll
            for (int ct = 0; ct < 8; ct++)
                #pragma unroll
                for (int reg = 0; reg < 4; reg++)
                    pm = fmaxf(pm, S[ct][ns][reg]);
            pm = fmaxf(pm, __shfl_xor(pm, 16));
            pm = fmaxf(pm, __shfl_xor(pm, 32));
            float mn = fmaxf(m_r[ns], pm);
            alpha[ns] = exp2f(m_r[ns] - mn);
            m_r[ns] = mn;
            #pragma unroll
            for (int ctd = 0; ctd < 4; ctd++)
                Oacc[ctd][ns] *= alpha[ns];
        }

        // exp2 -> pack bf16 P fragment in-register -> PV (16x16x16 MFMAs)
        #pragma unroll
        for (int ct = 0; ct < 8; ct++) {
            #pragma unroll
            for (int ns = 0; ns < 2; ns++) {
                float p0 = exp2f(S[ct][ns][0] - m_r[ns]);
                float p1 = exp2f(S[ct][ns][1] - m_r[ns]);
                float p2 = exp2f(S[ct][ns][2] - m_r[ns]);
                float p3 = exp2f(S[ct][ns][3] - m_r[ns]);
                ssum[ns] += (p0 + p1) + (p2 + p3);
                B4 pb;
                pb.u.x = pk2bf(p0, p1);
                pb.u.y = pk2bf(p2, p3);
                #pragma unroll
                for (int ctd = 0; ctd < 4; ctd++)
                    Oacc[ctd][ns] = pv_mfma(vfr[ct][ctd], pb, Oacc[ctd][ns]);
            }
        }
        #pragma unroll
        for (int ns = 0; ns < 2; ns++) {
            float s = ssum[ns];
            s += __shfl_xor(s, 16);
            s += __shfl_xor(s, 32);
            l_r[ns] = l_r[ns] * alpha[ns] + s;
        }
        cur ^= 1;
    }

    // epilogue: bf16 attn_out [B*T][C]; lane ln = token, regs = d
    #pragma unroll
    for (int ns = 0; ns < 2; ns++) {
        float inv = 1.0f / l_r[ns];
        int token = q0 + wave * 32 + ns * 16 + ln;
        ushort* dst = Ob + ((size_t)(b_ * Tn + token)) * Cn + h * 64;
        #pragma unroll
        for (int ctd = 0; ctd < 4; ctd++) {
            ushort4 o;
            #pragma unroll
            for (int reg = 0; reg < 4; reg++)
                ((ushort*)&o)[reg] = f2bf(Oacc[ctd][ns][reg] * inv);
            *(ushort4*)&dst[ctd * 16 + quad * 4] = o;
        }
    }
    #undef STAGE_K
}

// ---------------------------------------------------------------------------
extern "C" void kernel_launch(void* const* d_in, const int* in_sizes, int n_in,
                              void* d_out, int out_size, void* d_ws, size_t ws_size,
                              hipStream_t stream) {
    const float* X     = (const float*)d_in[0];
    const float* qkv_w = (const float*)d_in[1];
    const float* qkv_b = (const float*)d_in[2];
    const float* o_w   = (const float*)d_in[3];
    const float* o_b   = (const float*)d_in[4];
    float* out = (float*)d_out;

    const size_t BTC = (size_t)Bn * Tn * Cn;     // 8388608
    ushort* Xb  = (ushort*)d_ws;                 // bf16 [8192,1024]
    ushort* Wqt = Xb  + BTC;                     // bf16 [3072,1024]
    ushort* Wot = Wqt + 3 * Cn * Cn;             // bf16 [1024,1024]
    ushort* Qb  = Wot + Cn * Cn;                 // bf16 [B,H,T,D]
    ushort* Kb  = Qb  + BTC;
    ushort* Vtb = Kb  + BTC;                     // bf16 [B,H,D,T]
    ushort* Ao  = Vtb + BTC;                     // bf16 [B*T,C]

    cvt_bf16<<<dim3((int)(BTC / 8 / 256)), 256, 0, stream>>>(X, Xb, (int)BTC);
    transpose_bf16<<<dim3(3 * Cn / 32, Kdim / 32), 256, 0, stream>>>(qkv_w, Wqt, 3 * Cn);
    transpose_bf16<<<dim3(Cn / 32, Kdim / 32), 256, 0, stream>>>(o_w, Wot, Cn);

    gemm_bt<1><<<dim3(3 * Cn / 128, 8192 / 128), 256, 0, stream>>>(
        Xb, Wqt, qkv_b, nullptr, Qb, Kb, Vtb);
    attn_mfma<<<dim3(Bn * Hn, 16), 256, 0, stream>>>(Qb, Kb, Vtb, Ao);
    gemm_bt<0><<<dim3(Cn / 128, 8192 / 128), 256, 0, stream>>>(
        Ao, Wot, o_b, out, nullptr, nullptr, nullptr);
}

// Round 12
// 305.548 us; speedup vs baseline: 1.1289x; 1.1192x over previous
//
#include <hip/hip_runtime.h>
#include <hip/hip_bf16.h>

// Problem constants
#define Bn 4
#define Tn 2048
#define Cn 1024
#define Hn 16
#define Dn 64
#define Kdim 1024

typedef __bf16 bf16x8 __attribute__((ext_vector_type(8)));
typedef float f32x4 __attribute__((ext_vector_type(4)));
union B8 { uint4 u; bf16x8 f; ushort s[8]; };

static __device__ __forceinline__ ushort f2bf(float x) {
    __hip_bfloat16 h = __float2bfloat16(x);
    return *(ushort*)&h;
}

#define AS1 __attribute__((address_space(1)))
#define AS3 __attribute__((address_space(3)))

static __device__ __forceinline__ void gload_lds16(const ushort* g, ushort* l) {
    __builtin_amdgcn_global_load_lds((AS1 const uint4*)(const void*)g,
                                     (AS3 uint4*)(void*)l, 16, 0, 0);
}

// ---------------------------------------------------------------------------
// Fused prep: grid.y selects section.
//  y==0 (4096 blocks): X fp32 -> bf16 (layout preserved)
//  y==1 (96x32 via blockIdx.x): qkv_w [K,3C] -> Wqt [3C,K] bf16
//  y==2 (32x32): o_w [K,C] -> Wot [C,K] bf16
// ---------------------------------------------------------------------------
__global__ __launch_bounds__(256) void prep_fused(
    const float* __restrict__ X, const float* __restrict__ qkv_w,
    const float* __restrict__ o_w,
    ushort* __restrict__ Xb, ushort* __restrict__ Wqt, ushort* __restrict__ Wot)
{
    if (blockIdx.y == 0) {
        int i = (blockIdx.x * 256 + threadIdx.x) * 8;
        float4 a = *(const float4*)&X[i];
        float4 b = *(const float4*)&X[i + 4];
        ushort4 o0, o1;
        o0.x = f2bf(a.x); o0.y = f2bf(a.y); o0.z = f2bf(a.z); o0.w = f2bf(a.w);
        o1.x = f2bf(b.x); o1.y = f2bf(b.y); o1.z = f2bf(b.z); o1.w = f2bf(b.w);
        *(ushort4*)&Xb[i] = o0;
        *(ushort4*)&Xb[i + 4] = o1;
        return;
    }
    // transpose sections
    const float* W; ushort* Wt; int N, bx;
    if (blockIdx.y == 1) { W = qkv_w; Wt = Wqt; N = 3 * Cn; bx = blockIdx.x; }
    else                 { W = o_w;   Wt = Wot; N = Cn;     bx = blockIdx.x; }
    if (bx >= (N / 32) * 32) return;
    const int n0 = (bx % (N / 32)) * 32, k0 = (bx / (N / 32)) * 32;
    __shared__ float Ls[32][33];
    const int tx = threadIdx.x & 31, ty = threadIdx.x >> 5;
    #pragma unroll
    for (int i = 0; i < 4; i++) {
        int r = ty + i * 8;
        Ls[r][tx] = W[(size_t)(k0 + r) * N + n0 + tx];
    }
    __syncthreads();
    #pragma unroll
    for (int i = 0; i < 4; i++) {
        int r = ty + i * 8;
        Wt[(size_t)(n0 + r) * Kdim + k0 + tx] = f2bf(Ls[tx][r]);
    }
}

// ---------------------------------------------------------------------------
// bf16 MFMA GEMM (m97 structure): C[M,N] = A[M,K] @ Bt[N,K]^T (+bias).
// EPI 0: fp32 out + bias.
// EPI 1: bf16 Q[B,H,T,D] (pre-scaled by D^-0.5*log2(e)), K[B,H,T,D],
//        V^T[B,H,D,T]. Epilogue round-trips each wave's 64x64 tile through
//        LDS (XOR bank swizzle) -> fully coalesced uint4 global stores.
// ---------------------------------------------------------------------------
template <int EPI>
__global__ __launch_bounds__(256) void gemm_bt(
    const ushort* __restrict__ A, const ushort* __restrict__ Bt,
    const float* __restrict__ bias,
    float* __restrict__ Out, ushort* __restrict__ Qb,
    ushort* __restrict__ Kb, ushort* __restrict__ Vtb)
{
    const int m0 = blockIdx.y * 128;
    const int n0 = blockIdx.x * 128;
    const int t  = threadIdx.x;
    const int wave = t >> 6, lane = t & 63;
    const int ln = lane & 15, quad = lane >> 4;
    const int wm = wave >> 1, wn = wave & 1;

    __shared__ ushort As[128 * 64];
    __shared__ ushort Bs[128 * 64];

    f32x4 acc[4][4] = {};

    for (int k0 = 0; k0 < Kdim; k0 += 64) {
        __syncthreads();
        #pragma unroll
        for (int it = 0; it < 4; it++) {
            int c = it * 256 + wave * 64 + lane;
            int row = c >> 3, seg = c & 7;
            int gseg = seg ^ (row & 7);
            gload_lds16(&A [(size_t)(m0 + row) * Kdim + k0 + gseg * 8], &As[c * 8]);
            gload_lds16(&Bt[(size_t)(n0 + row) * Kdim + k0 + gseg * 8], &Bs[c * 8]);
        }
        __syncthreads();

        #pragma unroll
        for (int ks = 0; ks < 2; ks++) {
            bf16x8 af[4], bf[4];
            #pragma unroll
            for (int mm = 0; mm < 4; mm++) {
                int row = wm * 64 + mm * 16 + ln;
                int seg = (ks * 4 + quad) ^ (ln & 7);
                B8 tmp; tmp.u = *(const uint4*)&As[row * 64 + seg * 8];
                af[mm] = tmp.f;
            }
            #pragma unroll
            for (int nn = 0; nn < 4; nn++) {
                int row = wn * 64 + nn * 16 + ln;
                int seg = (ks * 4 + quad) ^ (ln & 7);
                B8 tmp; tmp.u = *(const uint4*)&Bs[row * 64 + seg * 8];
                bf[nn] = tmp.f;
            }
            #pragma unroll
            for (int mm = 0; mm < 4; mm++)
                #pragma unroll
                for (int nn = 0; nn < 4; nn++)
                    acc[mm][nn] = __builtin_amdgcn_mfma_f32_16x16x32_bf16(
                        af[mm], bf[nn], acc[mm][nn], 0, 0, 0);
        }
    }

    if (EPI == 0) {
        #pragma unroll
        for (int nn = 0; nn < 4; nn++) {
            int n = n0 + wn * 64 + nn * 16 + ln;
            float bv = bias[n];
            #pragma unroll
            for (int mm = 0; mm < 4; mm++) {
                int mbase = m0 + wm * 64 + mm * 16 + quad * 4;
                #pragma unroll
                for (int reg = 0; reg < 4; reg++)
                    Out[(size_t)(mbase + reg) * 1024 + n] = acc[mm][nn][reg] + bv;
            }
        }
    } else {
        const int nb = n0 + wn * 64;
        const int which = nb >> 10;            // 0=Q 1=K 2=V
        const int h = (nb & 1023) >> 6;
        const float scale = (which == 0) ? 0.125f * 1.44269504088896f : 1.0f;
        const int b_ = m0 >> 11;               // 128-row tile within one batch
        const int t0 = (m0 & 2047) + wm * 64;

        __syncthreads();   // fragments consumed; reuse As/Bs as transpose pads
        ushort* tile = ((wave & 2) ? Bs : As) + (wave & 1) * 4096;  // 64x64/wave

        if (which == 2) {
            // LDS tile [n=d][m=token] (XOR-swizzled), rows -> [B,H,D,T]
            #pragma unroll
            for (int nn = 0; nn < 4; nn++) {
                float bv = bias[nb + nn * 16 + ln];
                #pragma unroll
                for (int mm = 0; mm < 4; mm++)
                    #pragma unroll
                    for (int reg = 0; reg < 4; reg++) {
                        int m = mm * 16 + quad * 4 + reg;
                        int n = nn * 16 + ln;
                        tile[n * 64 + (m ^ (((n >> 1) & 7) * 8))] =
                            f2bf(acc[mm][nn][reg] + bv);
                    }
            }
            #pragma unroll
            for (int it = 0; it < 8; it++) {
                int idx = it * 64 + lane;
                int row = idx >> 3, seg = idx & 7;   // row = d, seg = token/8
                uint4 v = *(const uint4*)&tile[row * 64 +
                              ((seg * 8) ^ (((row >> 1) & 7) * 8))];
                *(uint4*)&Vtb[((size_t)((b_ * Hn + h) * Dn) + row) * Tn + t0 + seg * 8] = v;
            }
        } else {
            // LDS tile [m=token][n=d] (XOR-swizzled), rows -> [B,H,T,D]
            ushort* dst = (which == 0) ? Qb : Kb;
            #pragma unroll
            for (int nn = 0; nn < 4; nn++) {
                float bv = bias[nb + nn * 16 + ln];
                #pragma unroll
                for (int mm = 0; mm < 4; mm++)
                    #pragma unroll
                    for (int reg = 0; reg < 4; reg++) {
                        int m = mm * 16 + quad * 4 + reg;
                        int n = nn * 16 + ln;
                        tile[m * 64 + (n ^ (((m >> 1) & 7) * 8))] =
                            f2bf((acc[mm][nn][reg] + bv) * scale);
                    }
            }
            #pragma unroll
            for (int it = 0; it < 8; it++) {
                int idx = it * 64 + lane;
                int row = idx >> 3, seg = idx & 7;   // row = token, seg = d/8
                uint4 v = *(const uint4*)&tile[row * 64 +
                              ((seg * 8) ^ (((row >> 1) & 7) * 8))];
                *(uint4*)&dst[((size_t)((b_ * Hn + h) * Tn) + t0 + row) * Dn + seg * 8] = v;
            }
        }
    }
}

// ---------------------------------------------------------------------------
// Flash attention (r9/v6 — measured best 134 µs): one 128-row q-tile per
// block, grid (64,16) heavy-first. K double-buffered in LDS via
// global_load_lds prefetch; V^T direct global->VGPR; P staged in 32-key
// per-wave LDS slices (x32 PV MFMAs); one barrier per chunk; exp2 softmax.
// (256,2): forcing 3 waves/EU spills S (r10: WRITE 64MB, +42 µs); x16
// register-PV costs more pipe than the LDS slice (r11: +31 µs).
// ---------------------------------------------------------------------------
__global__ __launch_bounds__(256, 2) void attn_mfma(
    const ushort* __restrict__ Qb, const ushort* __restrict__ Kb,
    const ushort* __restrict__ Vtb, ushort* __restrict__ Ob)
{
    const int bh   = blockIdx.x;       // 0..63 (fastest-varying)
    const int qt   = 15 - blockIdx.y;  // heavy tiles first in block-ID order
    const int t    = threadIdx.x;
    const int wave = t >> 6, lane = t & 63;
    const int ln   = lane & 15, quad = lane >> 4;

    __shared__ ushort Ks[2][128 * 64];  // [key][d], xor-swizzled segs, 2x16KB
    __shared__ ushort Ps[4][32 * 34];   // per-wave P slice [q][key(32)+pad]

    const ushort* KgB = Kb  + (size_t)bh * Tn * Dn;
    const ushort* VgB = Vtb + (size_t)bh * Dn * Tn;
    const int b_ = bh >> 4, h = bh & 15;

    #define STAGE_K(kc, buf)                                                   \
        do {                                                                   \
            _Pragma("unroll")                                                  \
            for (int it = 0; it < 4; it++) {                                   \
                int c = it * 256 + wave * 64 + lane;                           \
                int row = c >> 3, seg = c & 7;                                 \
                int gs = seg ^ (row & 7);                                      \
                gload_lds16(&KgB[(size_t)((kc) * 128 + row) * Dn + gs * 8],    \
                            &Ks[buf][c * 8]);                                  \
            }                                                                  \
        } while (0)

    int cur = 0;
    STAGE_K(0, 0);

    const int q0 = qt * 128;

    const ushort* Qg = Qb + ((size_t)bh * Tn + q0 + wave * 32) * Dn;
    bf16x8 qf[2][2];
    #pragma unroll
    for (int ns = 0; ns < 2; ns++)
        #pragma unroll
        for (int ks = 0; ks < 2; ks++) {
            B8 tmp; tmp.u = *(const uint4*)&Qg[(ns * 16 + ln) * 64 + ks * 32 + quad * 8];
            qf[ns][ks] = tmp.f;
        }

    f32x4 Oacc[4][2] = {};   // O^T [d-subtile][ns], lane ln = q
    float m_r[2] = {-1e30f, -1e30f}, l_r[2] = {0.f, 0.f};

    for (int kc = 0; kc <= qt; kc++) {
        __syncthreads();   // publishes K(kc); drains prefetch issued last iter

        // V^T fragments: direct global->VGPR, A-layout natural in [B,H,D,T]
        B8 vfr[4][4];      // [d-subtile][32-key step]
        #pragma unroll
        for (int gks = 0; gks < 4; gks++)
            #pragma unroll
            for (int ctd = 0; ctd < 4; ctd++)
                vfr[ctd][gks].u = *(const uint4*)&VgB[
                    (size_t)(ctd * 16 + ln) * Tn + kc * 128 + gks * 32 + quad * 8];

        if (kc < qt) STAGE_K(kc + 1, cur ^ 1);   // prefetch next chunk

        // S^T = K Q^T: rows = keys (128 = 8 ct), cols = q (32 = 2 ns)
        const ushort* Kc = Ks[cur];
        f32x4 S[8][2] = {};
        #pragma unroll
        for (int ks = 0; ks < 2; ks++)
            #pragma unroll
            for (int ct = 0; ct < 8; ct++) {
                B8 a; a.u = *(const uint4*)&Kc[(ct * 16 + ln) * 64 +
                                               (((ks * 4 + quad) ^ (ln & 7)) * 8)];
                #pragma unroll
                for (int ns = 0; ns < 2; ns++)
                    S[ct][ns] = __builtin_amdgcn_mfma_f32_16x16x32_bf16(
                        a.f, qf[ns][ks], S[ct][ns], 0, 0, 0);
            }

        if (kc == qt) {   // causal mask on diagonal chunk
            #pragma unroll
            for (int ct = 0; ct < 8; ct++) {
                int keyl = ct * 16 + quad * 4;
                #pragma unroll
                for (int ns = 0; ns < 2; ns++) {
                    int ql = wave * 32 + ns * 16 + ln;
                    #pragma unroll
                    for (int reg = 0; reg < 4; reg++)
                        if (keyl + reg > ql) S[ct][ns][reg] = -1e30f;
                }
            }
        }

        // per-lane online softmax stats (q = ln; reduce over quads)
        float alpha[2], ssum[2] = {0.f, 0.f};
        #pragma unroll
        for (int ns = 0; ns < 2; ns++) {
            float pm = -1e30f;
            #pragma unroll
            for (int ct = 0; ct < 8; ct++)
                #pragma unroll
                for (int reg = 0; reg < 4; reg++)
                    pm = fmaxf(pm, S[ct][ns][reg]);
            pm = fmaxf(pm, __shfl_xor(pm, 16));
            pm = fmaxf(pm, __shfl_xor(pm, 32));
            float mn = fmaxf(m_r[ns], pm);
            alpha[ns] = exp2f(m_r[ns] - mn);
            m_r[ns] = mn;
            #pragma unroll
            for (int ctd = 0; ctd < 4; ctd++)
                Oacc[ctd][ns] *= alpha[ns];
        }

        // 4 passes: write 32-key P slice, immediately consume with PV step
        ushort* Pw = Ps[wave];
        #pragma unroll
        for (int p = 0; p < 4; p++) {
            #pragma unroll
            for (int ct_h = 0; ct_h < 2; ct_h++) {
                int ct = p * 2 + ct_h;
                #pragma unroll
                for (int ns = 0; ns < 2; ns++) {
                    ushort4 o;
                    #pragma unroll
                    for (int reg = 0; reg < 4; reg++) {
                        float pv = exp2f(S[ct][ns][reg] - m_r[ns]);
                        ssum[ns] += pv;
                        ((ushort*)&o)[reg] = f2bf(pv);
                    }
                    *(ushort4*)&Pw[(ns * 16 + ln) * 34 + ct_h * 16 + quad * 4] = o;
                }
            }
            #pragma unroll
            for (int ns = 0; ns < 2; ns++) {
                B8 pfr; pfr.u = *(const uint4*)&Pw[(ns * 16 + ln) * 34 + quad * 8];
                #pragma unroll
                for (int ctd = 0; ctd < 4; ctd++)
                    Oacc[ctd][ns] = __builtin_amdgcn_mfma_f32_16x16x32_bf16(
                        vfr[ctd][p].f, pfr.f, Oacc[ctd][ns], 0, 0, 0);
            }
        }
        #pragma unroll
        for (int ns = 0; ns < 2; ns++) {
            float s = ssum[ns];
            s += __shfl_xor(s, 16);
            s += __shfl_xor(s, 32);
            l_r[ns] = l_r[ns] * alpha[ns] + s;
        }
        cur ^= 1;
    }

    // epilogue: bf16 attn_out [B*T][C]; lane ln = token, regs = d
    #pragma unroll
    for (int ns = 0; ns < 2; ns++) {
        float inv = 1.0f / l_r[ns];
        int token = q0 + wave * 32 + ns * 16 + ln;
        ushort* dst = Ob + ((size_t)(b_ * Tn + token)) * Cn + h * 64;
        #pragma unroll
        for (int ctd = 0; ctd < 4; ctd++) {
            ushort4 o;
            #pragma unroll
            for (int reg = 0; reg < 4; reg++)
                ((ushort*)&o)[reg] = f2bf(Oacc[ctd][ns][reg] * inv);
            *(ushort4*)&dst[ctd * 16 + quad * 4] = o;
        }
    }
    #undef STAGE_K
}

// ---------------------------------------------------------------------------
extern "C" void kernel_launch(void* const* d_in, const int* in_sizes, int n_in,
                              void* d_out, int out_size, void* d_ws, size_t ws_size,
                              hipStream_t stream) {
    const float* X     = (const float*)d_in[0];
    const float* qkv_w = (const float*)d_in[1];
    const float* qkv_b = (const float*)d_in[2];
    const float* o_w   = (const float*)d_in[3];
    const float* o_b   = (const float*)d_in[4];
    float* out = (float*)d_out;

    const size_t BTC = (size_t)Bn * Tn * Cn;     // 8388608
    ushort* Xb  = (ushort*)d_ws;                 // bf16 [8192,1024]
    ushort* Wqt = Xb  + BTC;                     // bf16 [3072,1024]
    ushort* Wot = Wqt + 3 * Cn * Cn;             // bf16 [1024,1024]
    ushort* Qb  = Wot + Cn * Cn;                 // bf16 [B,H,T,D]
    ushort* Kb  = Qb  + BTC;
    ushort* Vtb = Kb  + BTC;                     // bf16 [B,H,D,T]
    ushort* Ao  = Vtb + BTC;                     // bf16 [B*T,C]

    // fused prep: y=0 cast (4096 blocks), y=1 qkv_w transpose (96*32=3072),
    // y=2 o_w transpose (32*32=1024). grid.x = max section size.
    prep_fused<<<dim3(4096, 3), 256, 0, stream>>>(X, qkv_w, o_w, Xb, Wqt, Wot);

    gemm_bt<1><<<dim3(3 * Cn / 128, 8192 / 128), 256, 0, stream>>>(
        Xb, Wqt, qkv_b, nullptr, Qb, Kb, Vtb);
    attn_mfma<<<dim3(Bn * Hn, 16), 256, 0, stream>>>(Qb, Kb, Vtb, Ao);
    gemm_bt<0><<<dim3(Cn / 128, 8192 / 128), 256, 0, stream>>>(
        Ao, Wot, o_b, out, nullptr, nullptr, nullptr);
}